// Round 1
// baseline (113.447 us; speedup 1.0000x reference)
//
#include <hip/hip_runtime.h>
#include <cstdint>
#include <cstddef>

// Problem constants
#define BB   2
#define SS   2048
#define DD   512
#define HH   8
#define HDIM 64
#define XN   ((size_t)BB * SS * DD)   // 2,097,152
#define WN   ((size_t)DD * DD)        //   262,144

typedef __attribute__((ext_vector_type(8)))  short          s16x8;
typedef __attribute__((ext_vector_type(8)))  unsigned short u16x8;
typedef __attribute__((ext_vector_type(16))) float          f32x16;

static __device__ __forceinline__ unsigned short f2bf(float f) {
  union { float f; unsigned u; } x; x.f = f;
  unsigned r = x.u + 0x7fffu + ((x.u >> 16) & 1u);  // RNE
  return (unsigned short)(r >> 16);
}
// truncating bf16 pack: result = bf(hi)<<16 | bf(lo), ONE v_perm_b32
static __device__ __forceinline__ unsigned packtrunc(float lo, float hi) {
  return __builtin_amdgcn_perm(__float_as_uint(hi), __float_as_uint(lo), 0x07060302u);
}

// sigmoid scale folded into Q: -1/sqrt(64) * log2(e)
#define QSCALE (-0.18033688011111543f)

// ---------------- fp32 -> bf16 conversion of weights ONLY --------------------------
// x conversion is now fused into proj (A-tile staged once per block, not 3x).
// grid (256, 3): 4.5 MB traffic total, ~1 us.
__global__ __launch_bounds__(256) void cvtw_kernel(
    const float* __restrict__ wq, const float* __restrict__ wk, const float* __restrict__ wv,
    unsigned short* __restrict__ wb3) {
  const int z = blockIdx.y;
  const float* src = (z == 0) ? wq : (z == 1) ? wk : wv;
  unsigned short* dst = wb3 + (size_t)z * WN;
  int i = (blockIdx.x * 256 + threadIdx.x) * 4;
  float4 f = *(const float4*)(src + i);
  ushort4 o;
  o.x = f2bf(f.x); o.y = f2bf(f.y); o.z = f2bf(f.z); o.w = f2bf(f.w);
  *(ushort4*)(dst + i) = o;
}

// ---------------- fused QKV projection (z-fused, x converted inline) ---------------
// grid (M/128=32, N/64=8) = 256 blocks = 1/CU. 256 threads = 4 waves; wave owns a
// 32-row strip x 64 cols for ALL THREE outputs (6 accs). BK=32, 16 iters, LDS dbuf +
// reg prefetch. A staged ONCE per kt (was 3x across z-blocks); A source is fp32 x,
// converted to bf16 during staging — the xb HBM round-trip is eliminated.
// Outputs: Q [B][H][S][HD] scaled; K MFMA A-frag order; V B-frag order with PI
// key permutation baked in (epilogues identical to the verified 3-kernel version).
__global__ __launch_bounds__(256, 1) void proj_kernel(
    const float* __restrict__ x, const unsigned short* __restrict__ wb3,
    const float* __restrict__ bq, const float* __restrict__ bk, const float* __restrict__ bv,
    unsigned short* __restrict__ qo, unsigned short* __restrict__ ko,
    unsigned short* __restrict__ vt) {
  __shared__ unsigned short As[2][128 * 40];
  __shared__ unsigned short Bs[2][3][64 * 40];

  const int t = threadIdx.x;
  const int lane = t & 63, wave = t >> 6;
  const int ln = lane & 31, hi = lane >> 5;
  const int m0 = blockIdx.x * 128, n0 = blockIdx.y * 64;

  // prefetch regs: A as fp32 (2 chunks x 8 floats), B as bf16 (3 weights)
  float4 axf[2][2];
  u16x8 br[3];
#pragma unroll
  for (int i = 0; i < 2; i++) {
    int c = t + i * 256;
    const float* ap = x + (size_t)(m0 + (c >> 2)) * DD + (c & 3) * 8;
    axf[i][0] = *(const float4*)ap;
    axf[i][1] = *(const float4*)(ap + 4);
  }
#pragma unroll
  for (int z = 0; z < 3; z++)
    br[z] = *(const u16x8*)&wb3[(size_t)z * WN + (size_t)(n0 + (t >> 2)) * DD + (t & 3) * 8];

#pragma unroll
  for (int i = 0; i < 2; i++) {
    int c = t + i * 256;
    u16x8 ar;
#pragma unroll
    for (int j = 0; j < 4; j++) {
      ar[j]     = f2bf(((const float*)&axf[i][0])[j]);
      ar[4 + j] = f2bf(((const float*)&axf[i][1])[j]);
    }
    *(u16x8*)&As[0][(c >> 2) * 40 + (c & 3) * 8] = ar;
  }
#pragma unroll
  for (int z = 0; z < 3; z++)
    *(u16x8*)&Bs[0][z][(t >> 2) * 40 + (t & 3) * 8] = br[z];
  __syncthreads();

  f32x16 acc[3][2];
#pragma unroll
  for (int z = 0; z < 3; z++) { acc[z][0] = (f32x16){}; acc[z][1] = (f32x16){}; }

#pragma unroll 2
  for (int kt = 0; kt < 16; kt++) {
    const int cur = kt & 1, nxt = cur ^ 1;
    if (kt < 15) {
      int k0 = (kt + 1) * 32;
#pragma unroll
      for (int i = 0; i < 2; i++) {
        int c = t + i * 256;
        const float* ap = x + (size_t)(m0 + (c >> 2)) * DD + k0 + (c & 3) * 8;
        axf[i][0] = *(const float4*)ap;
        axf[i][1] = *(const float4*)(ap + 4);
      }
#pragma unroll
      for (int z = 0; z < 3; z++)
        br[z] = *(const u16x8*)&wb3[(size_t)z * WN + (size_t)(n0 + (t >> 2)) * DD + k0 + (t & 3) * 8];
    }
#pragma unroll
    for (int cc = 0; cc < 2; cc++) {
      s16x8 af = *(const s16x8*)&As[cur][(wave * 32 + ln) * 40 + cc * 16 + hi * 8];
#pragma unroll
      for (int z = 0; z < 3; z++) {
        s16x8 b0 = *(const s16x8*)&Bs[cur][z][(ln) * 40 + cc * 16 + hi * 8];
        s16x8 b1 = *(const s16x8*)&Bs[cur][z][(32 + ln) * 40 + cc * 16 + hi * 8];
        acc[z][0] = __builtin_amdgcn_mfma_f32_32x32x16_bf16(af, b0, acc[z][0], 0, 0, 0);
        acc[z][1] = __builtin_amdgcn_mfma_f32_32x32x16_bf16(af, b1, acc[z][1], 0, 0, 0);
      }
    }
    if (kt < 15) {
#pragma unroll
      for (int i = 0; i < 2; i++) {
        int c = t + i * 256;
        u16x8 ar;
#pragma unroll
        for (int j = 0; j < 4; j++) {
          ar[j]     = f2bf(((const float*)&axf[i][0])[j]);
          ar[4 + j] = f2bf(((const float*)&axf[i][1])[j]);
        }
        *(u16x8*)&As[nxt][(c >> 2) * 40 + (c & 3) * 8] = ar;
      }
#pragma unroll
      for (int z = 0; z < 3; z++)
        *(u16x8*)&Bs[nxt][z][(t >> 2) * 40 + (t & 3) * 8] = br[z];
    }
    __syncthreads();
  }

  // ---- epilogues (identical layouts to the verified 3-kernel version) ----
  const int h = blockIdx.y;
  const int bidx = m0 >> 11;
  const int sbase = (m0 & 2047) + wave * 32;
  const size_t bhb = (size_t)(bidx * HH + h) * SS * HDIM;
  const int kts = sbase >> 5;

#pragma unroll
  for (int nh = 0; nh < 2; nh++) {
    const int hd = nh * 32 + ln;
    {  // z=0: Q, scaled, [B][H][S][HD]
      f32x16 av = acc[0][nh];
      const float bval = bq[n0 + hd];
#pragma unroll
      for (int r = 0; r < 16; r++) {
        int s = sbase + (r & 3) + 8 * (r >> 2) + 4 * hi;
        qo[bhb + (size_t)s * HDIM + hd] = f2bf((av[r] + bval) * QSCALE);
      }
    }
    {  // z=1: K, MFMA A-frag order
      f32x16 av = acc[1][nh];
      const float bval = bk[n0 + hd];
      const int c = hd >> 4, hk = (hd >> 3) & 1, j = hd & 7;
      unsigned short* kd = ko + bhb + ((size_t)kts * 4 + c) * 512 + j;
#pragma unroll
      for (int r = 0; r < 16; r++) {
        int off = (r & 3) + 8 * (r >> 2) + 4 * hi;
        kd[(hk * 32 + off) * 8] = f2bf(av[r] + bval);
      }
    }
    {  // z=2: V, B-frag order with PI key permutation
      f32x16 av = acc[2][nh];
      const float bval = bv[n0 + hd];
      unsigned short* vd = vt + bhb + ((size_t)kts * 4 + nh * 2) * 512 + hi * 256 + ln * 8;
#pragma unroll
      for (int g = 0; g < 4; g++) {
        unsigned short* vg = vd + (g >> 1) * 512 + (g & 1) * 4;
#pragma unroll
        for (int j2 = 0; j2 < 4; j2 += 2) {
          unsigned pk = (unsigned)f2bf(av[g * 4 + j2] + bval) |
                        ((unsigned)f2bf(av[g * 4 + j2 + 1] + bval) << 16);
          *(unsigned*)&vg[j2] = pk;
        }
      }
    }
  }
}

// ---------------- fused sigmoid attention: 64q per WAVE (traffic halved) ------------
// grid (S/128=16, B*H=16) = 256 blocks x 512 thr = 8 waves = (qp,kh) 2x4: each wave
// holds TWO 32-q sets (qp half = 64 queries) x key quarter (16 tiles of 32). Each K/V
// tile load now feeds 16 MFMAs (was 8) -> VMEM operand traffic halves (512->256 MB);
// trans/MFMA demand invariant. Lost TLP (2 waves/SIMD at ~165 regs) is compensated by
// doubled intra-wave ILP: QK(qs1) overlaps sigmoid(qs0). Single-buffered rotation,
// pi-permuted V, zero loop barriers. 64 KB staged kh-reduction.
__global__ __launch_bounds__(512, 2) void attn_kernel(
    const unsigned short* __restrict__ qb,
    const unsigned short* __restrict__ kfb,
    const unsigned short* __restrict__ vfb,
    float* __restrict__ out) {
  __shared__ __align__(16) float red[2 * 8192];  // 64 KB, 2 slots of 128q x 64d

  const int t = threadIdx.x;
  const int lane = t & 63, wave = t >> 6;   // wave 0..7
  const int ln = lane & 31, hi = lane >> 5;
  const int qp = wave & 1, kh = wave >> 1;  // qp: 64-q half, kh: key quarter
  // XCD swizzle: blocks of one bh at ids ≡ mod 16 -> same XCD
  const int fid = blockIdx.y * 16 + blockIdx.x;
  const int bh = fid & 15, qx = fid >> 4;
  const int b = bh >> 3, h = bh & 7;
  const unsigned short* qp_ = qb + (size_t)bh * SS * HDIM;
  const unsigned short* kfp = kfb + (size_t)bh * SS * HDIM;
  const unsigned short* vfp = vfb + (size_t)bh * SS * HDIM;
  const int q0 = qx * 128 + qp * 64;

  // TWO Q fragment sets (B-operand: n=q on lane, k=d)
  s16x8 qf[2][4];
#pragma unroll
  for (int qs = 0; qs < 2; qs++)
#pragma unroll
    for (int c = 0; c < 4; c++)
      qf[qs][c] = *(const s16x8*)&qp_[(size_t)(q0 + qs * 32 + ln) * HDIM + c * 16 + hi * 8];

  f32x16 o00 = {}, o01 = {}, o10 = {}, o11 = {};

  s16x8 kf[4], vf[4];
  int foff = kh * 16 * 2048 + lane * 8;
#pragma unroll
  for (int c = 0; c < 4; c++) {
    kf[c] = *(const s16x8*)&kfp[foff + c * 512];
    vf[c] = *(const s16x8*)&vfp[foff + c * 512];
  }
  foff += 2048;

#pragma unroll 1
  for (int i = 0; i < 16; i++) {
    // QK^T for both q-sets (independent chains — ILP)
    f32x16 st0 = {}, st1 = {};
#pragma unroll
    for (int c = 0; c < 4; c++) {
      st0 = __builtin_amdgcn_mfma_f32_32x32x16_bf16(kf[c], qf[0][c], st0, 0, 0, 0);
      st1 = __builtin_amdgcn_mfma_f32_32x32x16_bf16(kf[c], qf[1][c], st1, 0, 0, 0);
    }

    // kf dead -> rotate next tile's K (covered by sigmoid+PV)
    if (i < 15) {
#pragma unroll
      for (int c = 0; c < 4; c++)
        kf[c] = *(const s16x8*)&kfp[foff + c * 512];
    }

    // sigmoid both sets; pi layout -> pg[qs][4c..4c+3] is the PV A-operand verbatim
    unsigned pg[2][8];
#pragma unroll
    for (int qs = 0; qs < 2; qs++) {
      f32x16 st = qs ? st1 : st0;
#pragma unroll
      for (int g = 0; g < 4; g++) {
        float p0 = __builtin_amdgcn_rcpf(1.0f + __builtin_amdgcn_exp2f(st[4 * g + 0]));
        float p1 = __builtin_amdgcn_rcpf(1.0f + __builtin_amdgcn_exp2f(st[4 * g + 1]));
        float p2 = __builtin_amdgcn_rcpf(1.0f + __builtin_amdgcn_exp2f(st[4 * g + 2]));
        float p3 = __builtin_amdgcn_rcpf(1.0f + __builtin_amdgcn_exp2f(st[4 * g + 3]));
        pg[qs][2 * g]     = packtrunc(p0, p1);
        pg[qs][2 * g + 1] = packtrunc(p2, p3);
      }
    }

    // PV: 8 MFMAs reusing the same vf for both q-sets
#pragma unroll
    for (int c = 0; c < 2; c++) {
#pragma unroll
      for (int qs = 0; qs < 2; qs++) {
        union { unsigned u[4]; s16x8 v; } pu;
        pu.u[0] = pg[qs][4 * c + 0];
        pu.u[1] = pg[qs][4 * c + 1];
        pu.u[2] = pg[qs][4 * c + 2];
        pu.u[3] = pg[qs][4 * c + 3];
        if (qs == 0) {
          o00 = __builtin_amdgcn_mfma_f32_32x32x16_bf16(pu.v, vf[c], o00, 0, 0, 0);
          o01 = __builtin_amdgcn_mfma_f32_32x32x16_bf16(pu.v, vf[2 + c], o01, 0, 0, 0);
        } else {
          o10 = __builtin_amdgcn_mfma_f32_32x32x16_bf16(pu.v, vf[c], o10, 0, 0, 0);
          o11 = __builtin_amdgcn_mfma_f32_32x32x16_bf16(pu.v, vf[2 + c], o11, 0, 0, 0);
        }
      }
    }

    // vf dead -> rotate next tile's V (covered by next QK+sigmoid)
    if (i < 15) {
#pragma unroll
      for (int c = 0; c < 4; c++)
        vf[c] = *(const s16x8*)&vfp[foff + c * 512];
      foff += 2048;
    }
  }

  // staged 4-way kh reduction: kh{2,3} -> slots, kh{0,1} add, then pairwise sum.
  // slot index: 128q x 64d, q_local = qp*64 + qs*32 + C-row
  if (kh >= 2) {
    float* slot = red + (kh - 2) * 8192;
#pragma unroll
    for (int qs = 0; qs < 2; qs++)
#pragma unroll
      for (int dh = 0; dh < 2; dh++) {
        f32x16 ov = qs ? (dh ? o11 : o10) : (dh ? o01 : o00);
#pragma unroll
        for (int r = 0; r < 16; r++) {
          int ql = qp * 64 + qs * 32 + (r & 3) + 8 * (r >> 2) + 4 * hi;
          slot[ql * 64 + dh * 32 + ln] = ov[r];
        }
      }
  }
  __syncthreads();
  if (kh < 2) {
    float* slot = red + kh * 8192;
#pragma unroll
    for (int qs = 0; qs < 2; qs++)
#pragma unroll
      for (int dh = 0; dh < 2; dh++) {
        f32x16 ov = qs ? (dh ? o11 : o10) : (dh ? o01 : o00);
#pragma unroll
        for (int r = 0; r < 16; r++) {
          int ql = qp * 64 + qs * 32 + (r & 3) + 8 * (r >> 2) + 4 * hi;
          slot[ql * 64 + dh * 32 + ln] += ov[r];
        }
      }
  }
  __syncthreads();
  const float4* r0 = (const float4*)red;
  const float4* r1 = (const float4*)(red + 8192);
  const int qblk = qx * 128;
#pragma unroll
  for (int j = 0; j < 4; j++) {
    int g = t + j * 512;   // 2048 float4s total (128q x 64d)
    float4 s0 = r0[g], s1 = r1[g];
    float4 s;
    s.x = s0.x + s1.x; s.y = s0.y + s1.y; s.z = s0.z + s1.z; s.w = s0.w + s1.w;
    int q = g >> 4, dbase = (g & 15) * 4;
    *(float4*)&out[((size_t)(b * SS + qblk + q)) * DD + h * HDIM + dbase] = s;
  }
}

extern "C" void kernel_launch(void* const* d_in, const int* in_sizes, int n_in,
                              void* d_out, int out_size, void* d_ws, size_t ws_size,
                              hipStream_t stream) {
  const float* x  = (const float*)d_in[0];
  const float* wq = (const float*)d_in[1];
  const float* bq = (const float*)d_in[2];
  const float* wk = (const float*)d_in[3];
  const float* bk = (const float*)d_in[4];
  const float* wv = (const float*)d_in[5];
  const float* bv = (const float*)d_in[6];
  float* out = (float*)d_out;

  unsigned short* wb = (unsigned short*)d_ws;
  unsigned short* qo = wb + 3 * WN;
  unsigned short* ko = qo + XN;
  unsigned short* vt = ko + XN;   // ~13.5 MB total ws use (xb eliminated)

  cvtw_kernel<<<dim3(256, 3), 256, 0, stream>>>(wq, wk, wv, wb);
  proj_kernel<<<dim3(32, 8), 256, 0, stream>>>(x, wb, bq, bk, bv, qo, ko, vt);
  attn_kernel<<<dim3(SS / 128, BB * HH), 512, 0, stream>>>(qo, ko, vt, out);
}

// Round 2
// 113.339 us; speedup vs baseline: 1.0010x; 1.0010x over previous
//
#include <hip/hip_runtime.h>
#include <cstdint>
#include <cstddef>

// Problem constants
#define BB   2
#define SS   2048
#define DD   512
#define HH   8
#define HDIM 64
#define XN   ((size_t)BB * SS * DD)   // 2,097,152
#define WN   ((size_t)DD * DD)        //   262,144

typedef __attribute__((ext_vector_type(8)))  short          s16x8;
typedef __attribute__((ext_vector_type(8)))  unsigned short u16x8;
typedef __attribute__((ext_vector_type(16))) float          f32x16;

static __device__ __forceinline__ unsigned short f2bf(float f) {
  union { float f; unsigned u; } x; x.f = f;
  unsigned r = x.u + 0x7fffu + ((x.u >> 16) & 1u);  // RNE
  return (unsigned short)(r >> 16);
}
// truncating bf16 pack: result = bf(hi)<<16 | bf(lo), ONE v_perm_b32
static __device__ __forceinline__ unsigned packtrunc(float lo, float hi) {
  return __builtin_amdgcn_perm(__float_as_uint(hi), __float_as_uint(lo), 0x07060302u);
}

// sigmoid scale folded into Q: -1/sqrt(64) * log2(e)
#define QSCALE (-0.18033688011111543f)

// ---------------- fp32 -> bf16 weights, emitted in MFMA B-FRAGMENT order -----------
// Layout per z-plane (WN shorts), per h (n0 = h*64), per kstep s (K=16 slice):
//   off = h*32768 + (k>>4)*1024 + ((n>>5)&1)*512 + (n&31)*16 + ((k>>3)&1)*8 + (k&7)
// so a wave's 64 lanes (ln=lane&31, hi=lane>>5) load one fragment as a fully
// coalesced 2 KB dwordx4 burst. One-time 1.5 MB permute; proj then needs NO LDS.
__global__ __launch_bounds__(256) void cvtw_kernel(
    const float* __restrict__ wq, const float* __restrict__ wk, const float* __restrict__ wv,
    unsigned short* __restrict__ wb3) {
  const int z = blockIdx.y;
  const float* src = (z == 0) ? wq : (z == 1) ? wk : wv;
  unsigned short* dst = wb3 + (size_t)z * WN;
  int i = (blockIdx.x * 256 + threadIdx.x) * 4;
  float4 f = *(const float4*)(src + i);
  int n = i >> 9, k = i & 511;   // 4 consecutive k, same hi-granule (k%4==0)
  int off = (n >> 6) * 32768 + (k >> 4) * 1024 + ((n >> 5) & 1) * 512 +
            (n & 31) * 16 + ((k >> 3) & 1) * 8 + (k & 7);
  ushort4 o;
  o.x = f2bf(f.x); o.y = f2bf(f.y); o.z = f2bf(f.z); o.w = f2bf(f.w);
  *(ushort4*)&dst[off] = o;
}

// ---------------- fused QKV projection — NO LDS, no barriers ------------------------
// grid (M/128=32, N/64=8) = 256 blocks, 256 thr = 4 waves; wave owns 32 rows x 64
// cols x 3 z (6 f32x16 accs). Per K-step (K=16, 32 steps): A-octet loaded straight
// from fp32 x (8 contiguous floats per lane -> inline f2bf), 6 B-frags loaded from
// pre-fragged weights (coalesced). Distance-2 register double-buffer covers ~200cy
// L2 latency at 1 wave/SIMD. Removes the former ~57KB/iter ds_read + 20KB/iter
// ds_write bound (~6us); new bound is L2 stream (x 64MB + w 48MB ~= 3.2us).
// Epilogue layouts identical to the verified version.
__global__ __launch_bounds__(256, 1) void proj_kernel(
    const float* __restrict__ x, const unsigned short* __restrict__ wfrag,
    const float* __restrict__ bq, const float* __restrict__ bk, const float* __restrict__ bv,
    unsigned short* __restrict__ qo, unsigned short* __restrict__ ko,
    unsigned short* __restrict__ vt) {
  const int t = threadIdx.x;
  const int lane = t & 63, wave = t >> 6;
  const int ln = lane & 31, hi = lane >> 5;
  const int m0 = blockIdx.x * 128;
  const int h = blockIdx.y;
  const int n0 = h * 64;

  const float* xp = x + (size_t)(m0 + wave * 32 + ln) * DD + hi * 8;
  const unsigned short* wp = wfrag + h * 32768 + ln * 16 + hi * 8;

  // distance-2 register pipeline
  float4 a4[2][2];
  s16x8 bfr[2][3][2];
#pragma unroll
  for (int s = 0; s < 2; s++) {
    a4[s][0] = *(const float4*)(xp + s * 16);
    a4[s][1] = *(const float4*)(xp + s * 16 + 4);
#pragma unroll
    for (int z = 0; z < 3; z++)
#pragma unroll
      for (int nh = 0; nh < 2; nh++)
        bfr[s][z][nh] = *(const s16x8*)&wp[z * (int)WN + s * 1024 + nh * 512];
  }

  f32x16 acc[3][2] = {};

#pragma unroll 2
  for (int s = 0; s < 32; s++) {
    const int cur = s & 1;
    s16x8 af;
#pragma unroll
    for (int j = 0; j < 4; j++) {
      af[j]     = (short)f2bf(((const float*)&a4[cur][0])[j]);
      af[4 + j] = (short)f2bf(((const float*)&a4[cur][1])[j]);
    }
#pragma unroll
    for (int z = 0; z < 3; z++)
#pragma unroll
      for (int nh = 0; nh < 2; nh++)
        acc[z][nh] = __builtin_amdgcn_mfma_f32_32x32x16_bf16(af, bfr[cur][z][nh], acc[z][nh], 0, 0, 0);
    if (s < 30) {
      a4[cur][0] = *(const float4*)(xp + (s + 2) * 16);
      a4[cur][1] = *(const float4*)(xp + (s + 2) * 16 + 4);
#pragma unroll
      for (int z = 0; z < 3; z++)
#pragma unroll
        for (int nh = 0; nh < 2; nh++)
          bfr[cur][z][nh] = *(const s16x8*)&wp[z * (int)WN + (s + 2) * 1024 + nh * 512];
    }
  }

  // ---- epilogues (identical layouts to the verified version) ----
  const int bidx = m0 >> 11;
  const int sbase = (m0 & 2047) + wave * 32;
  const size_t bhb = (size_t)(bidx * HH + h) * SS * HDIM;
  const int kts = sbase >> 5;

#pragma unroll
  for (int nh = 0; nh < 2; nh++) {
    const int hd = nh * 32 + ln;
    {  // z=0: Q, scaled, [B][H][S][HD]
      f32x16 av = acc[0][nh];
      const float bval = bq[n0 + hd];
#pragma unroll
      for (int r = 0; r < 16; r++) {
        int s = sbase + (r & 3) + 8 * (r >> 2) + 4 * hi;
        qo[bhb + (size_t)s * HDIM + hd] = f2bf((av[r] + bval) * QSCALE);
      }
    }
    {  // z=1: K, MFMA A-frag order
      f32x16 av = acc[1][nh];
      const float bval = bk[n0 + hd];
      const int c = hd >> 4, hk = (hd >> 3) & 1, j = hd & 7;
      unsigned short* kd = ko + bhb + ((size_t)kts * 4 + c) * 512 + j;
#pragma unroll
      for (int r = 0; r < 16; r++) {
        int off = (r & 3) + 8 * (r >> 2) + 4 * hi;
        kd[(hk * 32 + off) * 8] = f2bf(av[r] + bval);
      }
    }
    {  // z=2: V, B-frag order with PI key permutation
      f32x16 av = acc[2][nh];
      const float bval = bv[n0 + hd];
      unsigned short* vd = vt + bhb + ((size_t)kts * 4 + nh * 2) * 512 + hi * 256 + ln * 8;
#pragma unroll
      for (int g = 0; g < 4; g++) {
        unsigned short* vg = vd + (g >> 1) * 512 + (g & 1) * 4;
#pragma unroll
        for (int j2 = 0; j2 < 4; j2 += 2) {
          unsigned pk = (unsigned)f2bf(av[g * 4 + j2] + bval) |
                        ((unsigned)f2bf(av[g * 4 + j2 + 1] + bval) << 16);
          *(unsigned*)&vg[j2] = pk;
        }
      }
    }
  }
}

// ---------------- fused sigmoid attention: 64q per WAVE (traffic halved) ------------
// grid (S/128=16, B*H=16) = 256 blocks x 512 thr = 8 waves = (qp,kh) 2x4: each wave
// holds TWO 32-q sets (qp half = 64 queries) x key quarter (16 tiles of 32). Each K/V
// tile load feeds 16 MFMAs -> VMEM operand traffic 256 MB (L2-resident per XCD via
// swizzle); bound ~= L2 stream ~7.5us. Single-buffered rotation, pi-permuted V, zero
// loop barriers. 64 KB staged kh-reduction.
__global__ __launch_bounds__(512, 2) void attn_kernel(
    const unsigned short* __restrict__ qb,
    const unsigned short* __restrict__ kfb,
    const unsigned short* __restrict__ vfb,
    float* __restrict__ out) {
  __shared__ __align__(16) float red[2 * 8192];  // 64 KB, 2 slots of 128q x 64d

  const int t = threadIdx.x;
  const int lane = t & 63, wave = t >> 6;   // wave 0..7
  const int ln = lane & 31, hi = lane >> 5;
  const int qp = wave & 1, kh = wave >> 1;  // qp: 64-q half, kh: key quarter
  // XCD swizzle: blocks of one bh at ids ≡ mod 16 -> same XCD
  const int fid = blockIdx.y * 16 + blockIdx.x;
  const int bh = fid & 15, qx = fid >> 4;
  const int b = bh >> 3, h = bh & 7;
  const unsigned short* qp_ = qb + (size_t)bh * SS * HDIM;
  const unsigned short* kfp = kfb + (size_t)bh * SS * HDIM;
  const unsigned short* vfp = vfb + (size_t)bh * SS * HDIM;
  const int q0 = qx * 128 + qp * 64;

  // TWO Q fragment sets (B-operand: n=q on lane, k=d)
  s16x8 qf[2][4];
#pragma unroll
  for (int qs = 0; qs < 2; qs++)
#pragma unroll
    for (int c = 0; c < 4; c++)
      qf[qs][c] = *(const s16x8*)&qp_[(size_t)(q0 + qs * 32 + ln) * HDIM + c * 16 + hi * 8];

  f32x16 o00 = {}, o01 = {}, o10 = {}, o11 = {};

  s16x8 kf[4], vf[4];
  int foff = kh * 16 * 2048 + lane * 8;
#pragma unroll
  for (int c = 0; c < 4; c++) {
    kf[c] = *(const s16x8*)&kfp[foff + c * 512];
    vf[c] = *(const s16x8*)&vfp[foff + c * 512];
  }
  foff += 2048;

#pragma unroll 1
  for (int i = 0; i < 16; i++) {
    // QK^T for both q-sets (independent chains — ILP)
    f32x16 st0 = {}, st1 = {};
#pragma unroll
    for (int c = 0; c < 4; c++) {
      st0 = __builtin_amdgcn_mfma_f32_32x32x16_bf16(kf[c], qf[0][c], st0, 0, 0, 0);
      st1 = __builtin_amdgcn_mfma_f32_32x32x16_bf16(kf[c], qf[1][c], st1, 0, 0, 0);
    }

    // kf dead -> rotate next tile's K (covered by sigmoid+PV)
    if (i < 15) {
#pragma unroll
      for (int c = 0; c < 4; c++)
        kf[c] = *(const s16x8*)&kfp[foff + c * 512];
    }

    // sigmoid both sets; pi layout -> pg[qs][4c..4c+3] is the PV A-operand verbatim
    unsigned pg[2][8];
#pragma unroll
    for (int qs = 0; qs < 2; qs++) {
      f32x16 st = qs ? st1 : st0;
#pragma unroll
      for (int g = 0; g < 4; g++) {
        float p0 = __builtin_amdgcn_rcpf(1.0f + __builtin_amdgcn_exp2f(st[4 * g + 0]));
        float p1 = __builtin_amdgcn_rcpf(1.0f + __builtin_amdgcn_exp2f(st[4 * g + 1]));
        float p2 = __builtin_amdgcn_rcpf(1.0f + __builtin_amdgcn_exp2f(st[4 * g + 2]));
        float p3 = __builtin_amdgcn_rcpf(1.0f + __builtin_amdgcn_exp2f(st[4 * g + 3]));
        pg[qs][2 * g]     = packtrunc(p0, p1);
        pg[qs][2 * g + 1] = packtrunc(p2, p3);
      }
    }

    // PV: 8 MFMAs reusing the same vf for both q-sets
#pragma unroll
    for (int c = 0; c < 2; c++) {
#pragma unroll
      for (int qs = 0; qs < 2; qs++) {
        union { unsigned u[4]; s16x8 v; } pu;
        pu.u[0] = pg[qs][4 * c + 0];
        pu.u[1] = pg[qs][4 * c + 1];
        pu.u[2] = pg[qs][4 * c + 2];
        pu.u[3] = pg[qs][4 * c + 3];
        if (qs == 0) {
          o00 = __builtin_amdgcn_mfma_f32_32x32x16_bf16(pu.v, vf[c], o00, 0, 0, 0);
          o01 = __builtin_amdgcn_mfma_f32_32x32x16_bf16(pu.v, vf[2 + c], o01, 0, 0, 0);
        } else {
          o10 = __builtin_amdgcn_mfma_f32_32x32x16_bf16(pu.v, vf[c], o10, 0, 0, 0);
          o11 = __builtin_amdgcn_mfma_f32_32x32x16_bf16(pu.v, vf[2 + c], o11, 0, 0, 0);
        }
      }
    }

    // vf dead -> rotate next tile's V (covered by next QK+sigmoid)
    if (i < 15) {
#pragma unroll
      for (int c = 0; c < 4; c++)
        vf[c] = *(const s16x8*)&vfp[foff + c * 512];
      foff += 2048;
    }
  }

  // staged 4-way kh reduction: kh{2,3} -> slots, kh{0,1} add, then pairwise sum.
  // slot index: 128q x 64d, q_local = qp*64 + qs*32 + C-row
  if (kh >= 2) {
    float* slot = red + (kh - 2) * 8192;
#pragma unroll
    for (int qs = 0; qs < 2; qs++)
#pragma unroll
      for (int dh = 0; dh < 2; dh++) {
        f32x16 ov = qs ? (dh ? o11 : o10) : (dh ? o01 : o00);
#pragma unroll
        for (int r = 0; r < 16; r++) {
          int ql = qp * 64 + qs * 32 + (r & 3) + 8 * (r >> 2) + 4 * hi;
          slot[ql * 64 + dh * 32 + ln] = ov[r];
        }
      }
  }
  __syncthreads();
  if (kh < 2) {
    float* slot = red + kh * 8192;
#pragma unroll
    for (int qs = 0; qs < 2; qs++)
#pragma unroll
      for (int dh = 0; dh < 2; dh++) {
        f32x16 ov = qs ? (dh ? o11 : o10) : (dh ? o01 : o00);
#pragma unroll
        for (int r = 0; r < 16; r++) {
          int ql = qp * 64 + qs * 32 + (r & 3) + 8 * (r >> 2) + 4 * hi;
          slot[ql * 64 + dh * 32 + ln] += ov[r];
        }
      }
  }
  __syncthreads();
  const float4* r0 = (const float4*)red;
  const float4* r1 = (const float4*)(red + 8192);
  const int qblk = qx * 128;
#pragma unroll
  for (int j = 0; j < 4; j++) {
    int g = t + j * 512;   // 2048 float4s total (128q x 64d)
    float4 s0 = r0[g], s1 = r1[g];
    float4 s;
    s.x = s0.x + s1.x; s.y = s0.y + s1.y; s.z = s0.z + s1.z; s.w = s0.w + s1.w;
    int q = g >> 4, dbase = (g & 15) * 4;
    *(float4*)&out[((size_t)(b * SS + qblk + q)) * DD + h * HDIM + dbase] = s;
  }
}

extern "C" void kernel_launch(void* const* d_in, const int* in_sizes, int n_in,
                              void* d_out, int out_size, void* d_ws, size_t ws_size,
                              hipStream_t stream) {
  const float* x  = (const float*)d_in[0];
  const float* wq = (const float*)d_in[1];
  const float* bq = (const float*)d_in[2];
  const float* wk = (const float*)d_in[3];
  const float* bk = (const float*)d_in[4];
  const float* wv = (const float*)d_in[5];
  const float* bv = (const float*)d_in[6];
  float* out = (float*)d_out;

  unsigned short* wb = (unsigned short*)d_ws;
  unsigned short* qo = wb + 3 * WN;
  unsigned short* ko = qo + XN;
  unsigned short* vt = ko + XN;   // ~13.5 MB total ws use

  cvtw_kernel<<<dim3(256, 3), 256, 0, stream>>>(wq, wk, wv, wb);
  proj_kernel<<<dim3(32, 8), 256, 0, stream>>>(x, wb, bq, bk, bv, qo, ko, vt);
  attn_kernel<<<dim3(SS / 128, BB * HH), 512, 0, stream>>>(qo, ko, vt, out);
}

// Round 3
// 112.914 us; speedup vs baseline: 1.0047x; 1.0038x over previous
//
#include <hip/hip_runtime.h>
#include <cstdint>
#include <cstddef>

// Problem constants
#define BB   2
#define SS   2048
#define DD   512
#define HH   8
#define HDIM 64
#define XN   ((size_t)BB * SS * DD)   // 2,097,152
#define WN   ((size_t)DD * DD)        //   262,144

typedef __attribute__((ext_vector_type(8)))  short          s16x8;
typedef __attribute__((ext_vector_type(8)))  unsigned short u16x8;
typedef __attribute__((ext_vector_type(16))) float          f32x16;

static __device__ __forceinline__ unsigned short f2bf(float f) {
  union { float f; unsigned u; } x; x.f = f;
  unsigned r = x.u + 0x7fffu + ((x.u >> 16) & 1u);  // RNE
  return (unsigned short)(r >> 16);
}
// truncating bf16 pack: result = bf(hi)<<16 | bf(lo), ONE v_perm_b32
static __device__ __forceinline__ unsigned packtrunc(float lo, float hi) {
  return __builtin_amdgcn_perm(__float_as_uint(hi), __float_as_uint(lo), 0x07060302u);
}

// sigmoid scale folded into Q: -1/sqrt(64) * log2(e)
#define QSCALE (-0.18033688011111543f)

// ---------------- fused cvt+QKV projection (2 launches total now) -------------------
// grid (M/128=32, N/64=8) = 256 blocks = 1/CU. 256 threads = 4 waves; wave owns a
// 32-row strip x 64 cols for ALL THREE outputs (6 accs). BK=32, 16 iters, LDS dbuf +
// reg prefetch. BOTH A (x) and B (wq/wk/wv) are read as fp32 and converted to bf16
// inline during staging — the separate cvtw kernel and its launch gap are gone, as
// is the wfrag workspace round-trip. Staging/LDS/epilogue indexing identical to the
// harness-verified round-1 z-fused version.
__global__ __launch_bounds__(256, 1) void proj_kernel(
    const float* __restrict__ x,
    const float* __restrict__ wq, const float* __restrict__ wk, const float* __restrict__ wv,
    const float* __restrict__ bq, const float* __restrict__ bk, const float* __restrict__ bv,
    unsigned short* __restrict__ qo, unsigned short* __restrict__ ko,
    unsigned short* __restrict__ vt) {
  __shared__ unsigned short As[2][128 * 40];
  __shared__ unsigned short Bs[2][3][64 * 40];

  const int t = threadIdx.x;
  const int lane = t & 63, wave = t >> 6;
  const int ln = lane & 31, hi = lane >> 5;
  const int m0 = blockIdx.x * 128, n0 = blockIdx.y * 64;

  const float* wsrc[3] = {wq, wk, wv};

  // prefetch regs: A fp32 (2 chunks x 8 floats), B fp32 (3 weights x 8 floats)
  float4 axf[2][2];
  float4 bxf[3][2];
#pragma unroll
  for (int i = 0; i < 2; i++) {
    int c = t + i * 256;
    const float* ap = x + (size_t)(m0 + (c >> 2)) * DD + (c & 3) * 8;
    axf[i][0] = *(const float4*)ap;
    axf[i][1] = *(const float4*)(ap + 4);
  }
#pragma unroll
  for (int z = 0; z < 3; z++) {
    const float* bp = wsrc[z] + (size_t)(n0 + (t >> 2)) * DD + (t & 3) * 8;
    bxf[z][0] = *(const float4*)bp;
    bxf[z][1] = *(const float4*)(bp + 4);
  }

#pragma unroll
  for (int i = 0; i < 2; i++) {
    int c = t + i * 256;
    u16x8 ar;
#pragma unroll
    for (int j = 0; j < 4; j++) {
      ar[j]     = f2bf(((const float*)&axf[i][0])[j]);
      ar[4 + j] = f2bf(((const float*)&axf[i][1])[j]);
    }
    *(u16x8*)&As[0][(c >> 2) * 40 + (c & 3) * 8] = ar;
  }
#pragma unroll
  for (int z = 0; z < 3; z++) {
    u16x8 br;
#pragma unroll
    for (int j = 0; j < 4; j++) {
      br[j]     = f2bf(((const float*)&bxf[z][0])[j]);
      br[4 + j] = f2bf(((const float*)&bxf[z][1])[j]);
    }
    *(u16x8*)&Bs[0][z][(t >> 2) * 40 + (t & 3) * 8] = br;
  }
  __syncthreads();

  f32x16 acc[3][2];
#pragma unroll
  for (int z = 0; z < 3; z++) { acc[z][0] = (f32x16){}; acc[z][1] = (f32x16){}; }

#pragma unroll 2
  for (int kt = 0; kt < 16; kt++) {
    const int cur = kt & 1, nxt = cur ^ 1;
    if (kt < 15) {
      int k0 = (kt + 1) * 32;
#pragma unroll
      for (int i = 0; i < 2; i++) {
        int c = t + i * 256;
        const float* ap = x + (size_t)(m0 + (c >> 2)) * DD + k0 + (c & 3) * 8;
        axf[i][0] = *(const float4*)ap;
        axf[i][1] = *(const float4*)(ap + 4);
      }
#pragma unroll
      for (int z = 0; z < 3; z++) {
        const float* bp = wsrc[z] + (size_t)(n0 + (t >> 2)) * DD + k0 + (t & 3) * 8;
        bxf[z][0] = *(const float4*)bp;
        bxf[z][1] = *(const float4*)(bp + 4);
      }
    }
#pragma unroll
    for (int cc = 0; cc < 2; cc++) {
      s16x8 af = *(const s16x8*)&As[cur][(wave * 32 + ln) * 40 + cc * 16 + hi * 8];
#pragma unroll
      for (int z = 0; z < 3; z++) {
        s16x8 b0 = *(const s16x8*)&Bs[cur][z][(ln) * 40 + cc * 16 + hi * 8];
        s16x8 b1 = *(const s16x8*)&Bs[cur][z][(32 + ln) * 40 + cc * 16 + hi * 8];
        acc[z][0] = __builtin_amdgcn_mfma_f32_32x32x16_bf16(af, b0, acc[z][0], 0, 0, 0);
        acc[z][1] = __builtin_amdgcn_mfma_f32_32x32x16_bf16(af, b1, acc[z][1], 0, 0, 0);
      }
    }
    if (kt < 15) {
#pragma unroll
      for (int i = 0; i < 2; i++) {
        int c = t + i * 256;
        u16x8 ar;
#pragma unroll
        for (int j = 0; j < 4; j++) {
          ar[j]     = f2bf(((const float*)&axf[i][0])[j]);
          ar[4 + j] = f2bf(((const float*)&axf[i][1])[j]);
        }
        *(u16x8*)&As[nxt][(c >> 2) * 40 + (c & 3) * 8] = ar;
      }
#pragma unroll
      for (int z = 0; z < 3; z++) {
        u16x8 br;
#pragma unroll
        for (int j = 0; j < 4; j++) {
          br[j]     = f2bf(((const float*)&bxf[z][0])[j]);
          br[4 + j] = f2bf(((const float*)&bxf[z][1])[j]);
        }
        *(u16x8*)&Bs[nxt][z][(t >> 2) * 40 + (t & 3) * 8] = br;
      }
    }
    __syncthreads();
  }

  // ---- epilogues (identical layouts to the verified version) ----
  const int h = blockIdx.y;
  const int bidx = m0 >> 11;
  const int sbase = (m0 & 2047) + wave * 32;
  const size_t bhb = (size_t)(bidx * HH + h) * SS * HDIM;
  const int kts = sbase >> 5;

#pragma unroll
  for (int nh = 0; nh < 2; nh++) {
    const int hd = nh * 32 + ln;
    {  // z=0: Q, scaled, [B][H][S][HD]
      f32x16 av = acc[0][nh];
      const float bval = bq[n0 + hd];
#pragma unroll
      for (int r = 0; r < 16; r++) {
        int s = sbase + (r & 3) + 8 * (r >> 2) + 4 * hi;
        qo[bhb + (size_t)s * HDIM + hd] = f2bf((av[r] + bval) * QSCALE);
      }
    }
    {  // z=1: K, MFMA A-frag order
      f32x16 av = acc[1][nh];
      const float bval = bk[n0 + hd];
      const int c = hd >> 4, hk = (hd >> 3) & 1, j = hd & 7;
      unsigned short* kd = ko + bhb + ((size_t)kts * 4 + c) * 512 + j;
#pragma unroll
      for (int r = 0; r < 16; r++) {
        int off = (r & 3) + 8 * (r >> 2) + 4 * hi;
        kd[(hk * 32 + off) * 8] = f2bf(av[r] + bval);
      }
    }
    {  // z=2: V, B-frag order with PI key permutation
      f32x16 av = acc[2][nh];
      const float bval = bv[n0 + hd];
      unsigned short* vd = vt + bhb + ((size_t)kts * 4 + nh * 2) * 512 + hi * 256 + ln * 8;
#pragma unroll
      for (int g = 0; g < 4; g++) {
        unsigned short* vg = vd + (g >> 1) * 512 + (g & 1) * 4;
#pragma unroll
        for (int j2 = 0; j2 < 4; j2 += 2) {
          unsigned pk = (unsigned)f2bf(av[g * 4 + j2] + bval) |
                        ((unsigned)f2bf(av[g * 4 + j2 + 1] + bval) << 16);
          *(unsigned*)&vg[j2] = pk;
        }
      }
    }
  }
}

// ---------------- fused sigmoid attention: 64q per WAVE (traffic halved) ------------
// grid (S/128=16, B*H=16) = 256 blocks x 512 thr = 8 waves = (qp,kh) 2x4: each wave
// holds TWO 32-q sets (qp half = 64 queries) x key quarter (16 tiles of 32). Each K/V
// tile load feeds 16 MFMAs -> VMEM operand traffic 256 MB (L2-resident per XCD via
// swizzle); bound ~= L2 stream + MFMA floor (~7-8us). Single-buffered rotation,
// pi-permuted V, zero loop barriers. 64 KB staged kh-reduction.
__global__ __launch_bounds__(512, 2) void attn_kernel(
    const unsigned short* __restrict__ qb,
    const unsigned short* __restrict__ kfb,
    const unsigned short* __restrict__ vfb,
    float* __restrict__ out) {
  __shared__ __align__(16) float red[2 * 8192];  // 64 KB, 2 slots of 128q x 64d

  const int t = threadIdx.x;
  const int lane = t & 63, wave = t >> 6;   // wave 0..7
  const int ln = lane & 31, hi = lane >> 5;
  const int qp = wave & 1, kh = wave >> 1;  // qp: 64-q half, kh: key quarter
  // XCD swizzle: blocks of one bh at ids ≡ mod 16 -> same XCD
  const int fid = blockIdx.y * 16 + blockIdx.x;
  const int bh = fid & 15, qx = fid >> 4;
  const int b = bh >> 3, h = bh & 7;
  const unsigned short* qp_ = qb + (size_t)bh * SS * HDIM;
  const unsigned short* kfp = kfb + (size_t)bh * SS * HDIM;
  const unsigned short* vfp = vfb + (size_t)bh * SS * HDIM;
  const int q0 = qx * 128 + qp * 64;

  // TWO Q fragment sets (B-operand: n=q on lane, k=d)
  s16x8 qf[2][4];
#pragma unroll
  for (int qs = 0; qs < 2; qs++)
#pragma unroll
    for (int c = 0; c < 4; c++)
      qf[qs][c] = *(const s16x8*)&qp_[(size_t)(q0 + qs * 32 + ln) * HDIM + c * 16 + hi * 8];

  f32x16 o00 = {}, o01 = {}, o10 = {}, o11 = {};

  s16x8 kf[4], vf[4];
  int foff = kh * 16 * 2048 + lane * 8;
#pragma unroll
  for (int c = 0; c < 4; c++) {
    kf[c] = *(const s16x8*)&kfp[foff + c * 512];
    vf[c] = *(const s16x8*)&vfp[foff + c * 512];
  }
  foff += 2048;

#pragma unroll 1
  for (int i = 0; i < 16; i++) {
    // QK^T for both q-sets (independent chains — ILP)
    f32x16 st0 = {}, st1 = {};
#pragma unroll
    for (int c = 0; c < 4; c++) {
      st0 = __builtin_amdgcn_mfma_f32_32x32x16_bf16(kf[c], qf[0][c], st0, 0, 0, 0);
      st1 = __builtin_amdgcn_mfma_f32_32x32x16_bf16(kf[c], qf[1][c], st1, 0, 0, 0);
    }

    // kf dead -> rotate next tile's K (covered by sigmoid+PV)
    if (i < 15) {
#pragma unroll
      for (int c = 0; c < 4; c++)
        kf[c] = *(const s16x8*)&kfp[foff + c * 512];
    }

    // sigmoid both sets; pi layout -> pg[qs][4c..4c+3] is the PV A-operand verbatim
    unsigned pg[2][8];
#pragma unroll
    for (int qs = 0; qs < 2; qs++) {
      f32x16 st = qs ? st1 : st0;
#pragma unroll
      for (int g = 0; g < 4; g++) {
        float p0 = __builtin_amdgcn_rcpf(1.0f + __builtin_amdgcn_exp2f(st[4 * g + 0]));
        float p1 = __builtin_amdgcn_rcpf(1.0f + __builtin_amdgcn_exp2f(st[4 * g + 1]));
        float p2 = __builtin_amdgcn_rcpf(1.0f + __builtin_amdgcn_exp2f(st[4 * g + 2]));
        float p3 = __builtin_amdgcn_rcpf(1.0f + __builtin_amdgcn_exp2f(st[4 * g + 3]));
        pg[qs][2 * g]     = packtrunc(p0, p1);
        pg[qs][2 * g + 1] = packtrunc(p2, p3);
      }
    }

    // PV: 8 MFMAs reusing the same vf for both q-sets
#pragma unroll
    for (int c = 0; c < 2; c++) {
#pragma unroll
      for (int qs = 0; qs < 2; qs++) {
        union { unsigned u[4]; s16x8 v; } pu;
        pu.u[0] = pg[qs][4 * c + 0];
        pu.u[1] = pg[qs][4 * c + 1];
        pu.u[2] = pg[qs][4 * c + 2];
        pu.u[3] = pg[qs][4 * c + 3];
        if (qs == 0) {
          o00 = __builtin_amdgcn_mfma_f32_32x32x16_bf16(pu.v, vf[c], o00, 0, 0, 0);
          o01 = __builtin_amdgcn_mfma_f32_32x32x16_bf16(pu.v, vf[2 + c], o01, 0, 0, 0);
        } else {
          o10 = __builtin_amdgcn_mfma_f32_32x32x16_bf16(pu.v, vf[c], o10, 0, 0, 0);
          o11 = __builtin_amdgcn_mfma_f32_32x32x16_bf16(pu.v, vf[2 + c], o11, 0, 0, 0);
        }
      }
    }

    // vf dead -> rotate next tile's V (covered by next QK+sigmoid)
    if (i < 15) {
#pragma unroll
      for (int c = 0; c < 4; c++)
        vf[c] = *(const s16x8*)&vfp[foff + c * 512];
      foff += 2048;
    }
  }

  // staged 4-way kh reduction: kh{2,3} -> slots, kh{0,1} add, then pairwise sum.
  // slot index: 128q x 64d, q_local = qp*64 + qs*32 + C-row
  if (kh >= 2) {
    float* slot = red + (kh - 2) * 8192;
#pragma unroll
    for (int qs = 0; qs < 2; qs++)
#pragma unroll
      for (int dh = 0; dh < 2; dh++) {
        f32x16 ov = qs ? (dh ? o11 : o10) : (dh ? o01 : o00);
#pragma unroll
        for (int r = 0; r < 16; r++) {
          int ql = qp * 64 + qs * 32 + (r & 3) + 8 * (r >> 2) + 4 * hi;
          slot[ql * 64 + dh * 32 + ln] = ov[r];
        }
      }
  }
  __syncthreads();
  if (kh < 2) {
    float* slot = red + kh * 8192;
#pragma unroll
    for (int qs = 0; qs < 2; qs++)
#pragma unroll
      for (int dh = 0; dh < 2; dh++) {
        f32x16 ov = qs ? (dh ? o11 : o10) : (dh ? o01 : o00);
#pragma unroll
        for (int r = 0; r < 16; r++) {
          int ql = qp * 64 + qs * 32 + (r & 3) + 8 * (r >> 2) + 4 * hi;
          slot[ql * 64 + dh * 32 + ln] += ov[r];
        }
      }
  }
  __syncthreads();
  const float4* r0 = (const float4*)red;
  const float4* r1 = (const float4*)(red + 8192);
  const int qblk = qx * 128;
#pragma unroll
  for (int j = 0; j < 4; j++) {
    int g = t + j * 512;   // 2048 float4s total (128q x 64d)
    float4 s0 = r0[g], s1 = r1[g];
    float4 s;
    s.x = s0.x + s1.x; s.y = s0.y + s1.y; s.z = s0.z + s1.z; s.w = s0.w + s1.w;
    int q = g >> 4, dbase = (g & 15) * 4;
    *(float4*)&out[((size_t)(b * SS + qblk + q)) * DD + h * HDIM + dbase] = s;
  }
}

extern "C" void kernel_launch(void* const* d_in, const int* in_sizes, int n_in,
                              void* d_out, int out_size, void* d_ws, size_t ws_size,
                              hipStream_t stream) {
  const float* x  = (const float*)d_in[0];
  const float* wq = (const float*)d_in[1];
  const float* bq = (const float*)d_in[2];
  const float* wk = (const float*)d_in[3];
  const float* bk = (const float*)d_in[4];
  const float* wv = (const float*)d_in[5];
  const float* bv = (const float*)d_in[6];
  float* out = (float*)d_out;

  unsigned short* qo = (unsigned short*)d_ws;
  unsigned short* ko = qo + XN;
  unsigned short* vt = ko + XN;   // 12 MB total ws use (wfrag eliminated)

  proj_kernel<<<dim3(32, 8), 256, 0, stream>>>(x, wq, wk, wv, bq, bk, bv, qo, ko, vt);
  attn_kernel<<<dim3(SS / 128, BB * HH), 512, 0, stream>>>(qo, ko, vt, out);
}